// Round 1
// baseline (341.009 us; speedup 1.0000x reference)
//
#include <hip/hip_runtime.h>
#include <math.h>

#define SEQ      8192
#define NTHREADS 256
#define VPT      32           // values per thread
#define F4PT     8            // float4 per thread

__device__ __forceinline__ float wave_sum(float x) {
    #pragma unroll
    for (int off = 32; off > 0; off >>= 1)
        x += __shfl_xor(x, off, 64);
    return x;
}

__global__ __launch_bounds__(NTHREADS) void normalizer_kernel(
        const float* __restrict__ score,
        const int*   __restrict__ mask,
        float*       __restrict__ out)
{
    const int row  = blockIdx.x;
    const int tid  = threadIdx.x;
    const int wid  = tid >> 6;
    const int lane = tid & 63;

    const float4* __restrict__ s4 = (const float4*)(score + (size_t)row * SEQ);
    const int4*   __restrict__ m4 = (const int4*)(mask  + (size_t)row * SEQ);

    // Load row into registers, apply mask (-inf), count valid entries.
    float v[VPT];
    int cnt = 0;
    #pragma unroll
    for (int j = 0; j < F4PT; ++j) {
        float4 s = s4[j * NTHREADS + tid];
        int4   m = m4[j * NTHREADS + tid];
        v[4*j+0] = m.x ? s.x : -INFINITY;
        v[4*j+1] = m.y ? s.y : -INFINITY;
        v[4*j+2] = m.z ? s.z : -INFINITY;
        v[4*j+3] = m.w ? s.w : -INFINITY;
        cnt += (m.x != 0) + (m.y != 0) + (m.z != 0) + (m.w != 0);
    }

    // Per-phase LDS slots (21 phases): write -> barrier -> read, no reuse,
    // so a single __syncthreads per phase is hazard-free.
    __shared__ float red[21][4];

    float p = wave_sum((float)cnt);
    if (lane == 0) red[0][wid] = p;
    __syncthreads();
    const float k     = 0.1f * (red[0][0] + red[0][1] + red[0][2] + red[0][3]);
    const float log2k = __builtin_amdgcn_logf(k);   // v_log_f32 = log2

    constexpr double L2E = 1.4426950408889634;      // log2(e)
    constexpr double LN2 = 0.6931471805599453;

    // b = -relu(score + a)  =>  score + b = min(score, -a).
    // Track negA = -a; initial b=0 corresponds to negA = +inf.
    float  negA = INFINITY;
    double thd  = 4.0;                               // theta_t = max(0.7^t*4, 0.3)
    #pragma unroll
    for (int t = 0; t < 8; ++t) {                    // annealed thetas (t<8 unclamped)
        const float c    = (float)(L2E / thd);       // exp(x/th) = exp2(x*c)
        const float thl2 = (float)(thd * LN2);
        float part = 0.f;
        #pragma unroll
        for (int j = 0; j < VPT; ++j)
            part += __builtin_amdgcn_exp2f(fminf(v[j], negA) * c);
        part = wave_sum(part);
        if (lane == 0) red[1 + t][wid] = part;
        __syncthreads();
        const float s = red[1+t][0] + red[1+t][1] + red[1+t][2] + red[1+t][3];
        // -a = th * ln((s+eps)/k) = th*ln2 * (log2(s+eps) - log2(k))
        negA = thl2 * (__builtin_amdgcn_logf(s + 1e-20f) - log2k);
        thd *= 0.7;
    }

    // t >= 8: theta = 0.3 constant. Pre-scale into exp2 domain:
    //   w = v * (log2e/0.3),  NA = negA * (log2e/0.3)
    // update simplifies to NA = log2(s+eps) - log2(k).
    const float cf = (float)(L2E / 0.3);
    #pragma unroll
    for (int j = 0; j < VPT; ++j) v[j] *= cf;
    float NA = negA * cf;

    #pragma unroll
    for (int t = 8; t < 20; ++t) {
        float part = 0.f;
        #pragma unroll
        for (int j = 0; j < VPT; ++j)
            part += __builtin_amdgcn_exp2f(fminf(v[j], NA));
        part = wave_sum(part);
        if (lane == 0) red[1 + t][wid] = part;
        __syncthreads();
        const float s = red[1+t][0] + red[1+t][1] + red[1+t][2] + red[1+t][3];
        NA = __builtin_amdgcn_logf(s + 1e-20f) - log2k;
    }

    // gamma = exp((score+a+b)/0.3) = exp2(min(w - NA, 0)); 0 for masked.
    float4* __restrict__ o4 = (float4*)(out + (size_t)row * SEQ);
    #pragma unroll
    for (int j = 0; j < F4PT; ++j) {
        float w0 = v[4*j+0], w1 = v[4*j+1], w2 = v[4*j+2], w3 = v[4*j+3];
        float4 g;
        g.x = (w0 == -INFINITY) ? 0.f : __builtin_amdgcn_exp2f(fminf(w0 - NA, 0.f));
        g.y = (w1 == -INFINITY) ? 0.f : __builtin_amdgcn_exp2f(fminf(w1 - NA, 0.f));
        g.z = (w2 == -INFINITY) ? 0.f : __builtin_amdgcn_exp2f(fminf(w2 - NA, 0.f));
        g.w = (w3 == -INFINITY) ? 0.f : __builtin_amdgcn_exp2f(fminf(w3 - NA, 0.f));
        o4[j * NTHREADS + tid] = g;
    }
}

extern "C" void kernel_launch(void* const* d_in, const int* in_sizes, int n_in,
                              void* d_out, int out_size, void* d_ws, size_t ws_size,
                              hipStream_t stream) {
    const float* score = (const float*)d_in[0];
    const int*   mask  = (const int*)d_in[1];
    float*       out   = (float*)d_out;
    const int rows = in_sizes[0] / SEQ;   // 4096
    normalizer_kernel<<<rows, NTHREADS, 0, stream>>>(score, mask, out);
}

// Round 2
// 336.702 us; speedup vs baseline: 1.0128x; 1.0128x over previous
//
#include <hip/hip_runtime.h>
#include <math.h>

#define SEQ      8192
#define NTHREADS 256
#define VPT      32           // values per thread per row
#define F4PT     8            // float4 per thread per row
#define RPB      2            // rows per block

__device__ __forceinline__ float wave_sum(float x) {
    #pragma unroll
    for (int off = 32; off > 0; off >>= 1)
        x += __shfl_xor(x, off, 64);
    return x;
}

__global__ __launch_bounds__(NTHREADS) void normalizer_kernel(
        const float* __restrict__ score,
        const int*   __restrict__ mask,
        float*       __restrict__ out)
{
    const int row0 = blockIdx.x * RPB;
    const int tid  = threadIdx.x;
    const int wid  = tid >> 6;
    const int lane = tid & 63;

    constexpr double L2E = 1.4426950408889634;   // log2(e)
    const float cf = (float)(L2E / 0.3);         // score -> w domain

    const float4* __restrict__ sA = (const float4*)(score + (size_t)row0 * SEQ);
    const int4*   __restrict__ mA = (const int4*)(mask  + (size_t)row0 * SEQ);
    const float4* __restrict__ sB = (const float4*)(score + (size_t)(row0 + 1) * SEQ);
    const int4*   __restrict__ mB = (const int4*)(mask  + (size_t)(row0 + 1) * SEQ);

    // w = score * log2e/0.3, masked -> -inf (exp2(-inf)=0 handles everything later)
    float wA[VPT], wB[VPT];
    int cntA = 0, cntB = 0;
    #pragma unroll
    for (int j = 0; j < F4PT; ++j) {
        float4 s = sA[j * NTHREADS + tid];
        int4   m = mA[j * NTHREADS + tid];
        wA[4*j+0] = m.x ? s.x * cf : -INFINITY;
        wA[4*j+1] = m.y ? s.y * cf : -INFINITY;
        wA[4*j+2] = m.z ? s.z * cf : -INFINITY;
        wA[4*j+3] = m.w ? s.w * cf : -INFINITY;
        cntA += (m.x != 0) + (m.y != 0) + (m.z != 0) + (m.w != 0);
    }
    #pragma unroll
    for (int j = 0; j < F4PT; ++j) {
        float4 s = sB[j * NTHREADS + tid];
        int4   m = mB[j * NTHREADS + tid];
        wB[4*j+0] = m.x ? s.x * cf : -INFINITY;
        wB[4*j+1] = m.y ? s.y * cf : -INFINITY;
        wB[4*j+2] = m.z ? s.z * cf : -INFINITY;
        wB[4*j+3] = m.w ? s.w * cf : -INFINITY;
        cntB += (m.x != 0) + (m.y != 0) + (m.z != 0) + (m.w != 0);
    }

    // Per-phase LDS slots (no reuse -> one barrier per phase, hazard-free).
    __shared__ float red[21][RPB][4];

    float pA = wave_sum((float)cntA);
    float pB = wave_sum((float)cntB);
    if (lane == 0) { red[0][0][wid] = pA; red[0][1][wid] = pB; }
    __syncthreads();
    const float kA = 0.1f * (red[0][0][0] + red[0][0][1] + red[0][0][2] + red[0][0][3]);
    const float kB = 0.1f * (red[0][1][0] + red[0][1][1] + red[0][1][2] + red[0][1][3]);
    const float l2kA = __builtin_amdgcn_logf(kA);   // v_log_f32 = log2
    const float l2kB = __builtin_amdgcn_logf(kB);
    const float rkA  = 1.0f / kA;
    const float rkB  = 1.0f / kB;

    // NA = negA in w-domain (= -a * log2e/0.3). b=0 start -> NA=+inf.
    float NAa = INFINITY, NAb = INFINITY;

    // t = 0..7: theta unclamped. exp((min(score,-a))/th) = exp2(min(w,NA)*(0.3/th))
    double thd = 4.0;
    #pragma unroll
    for (int t = 0; t < 8; ++t) {
        const float cp  = (float)(0.3 / thd);      // compile-time folded
        const float inv = (float)(thd / 0.3);
        float a0 = 0.f, a1 = 0.f, b0 = 0.f, b1 = 0.f;
        #pragma unroll
        for (int j = 0; j < VPT; j += 2) {
            a0 += __builtin_amdgcn_exp2f(fminf(wA[j],   NAa) * cp);
            a1 += __builtin_amdgcn_exp2f(fminf(wA[j+1], NAa) * cp);
            b0 += __builtin_amdgcn_exp2f(fminf(wB[j],   NAb) * cp);
            b1 += __builtin_amdgcn_exp2f(fminf(wB[j+1], NAb) * cp);
        }
        float pa = wave_sum(a0 + a1);
        float pb = wave_sum(b0 + b1);
        if (lane == 0) { red[1+t][0][wid] = pa; red[1+t][1][wid] = pb; }
        __syncthreads();
        const float sA_ = red[1+t][0][0] + red[1+t][0][1] + red[1+t][0][2] + red[1+t][0][3];
        const float sB_ = red[1+t][1][0] + red[1+t][1][1] + red[1+t][1][2] + red[1+t][1][3];
        NAa = inv * (__builtin_amdgcn_logf(sA_ + 1e-20f) - l2kA);
        NAb = inv * (__builtin_amdgcn_logf(sB_ + 1e-20f) - l2kB);
        thd *= 0.7;
    }

    // Convert to e = exp2(w) in place (monotone: exp2(min(w,NA)) = min(e, eNA)).
    #pragma unroll
    for (int j = 0; j < VPT; ++j) {
        wA[j] = __builtin_amdgcn_exp2f(wA[j]);
        wB[j] = __builtin_amdgcn_exp2f(wB[j]);
    }
    float eNAa = __builtin_amdgcn_exp2f(NAa);
    float eNAb = __builtin_amdgcn_exp2f(NAb);

    // t = 8..19: theta = 0.3. s = sum(min(e, eNA)); eNA' = (s+eps)/k. No exps.
    #pragma unroll
    for (int t = 8; t < 20; ++t) {
        float a0 = 0.f, a1 = 0.f, b0 = 0.f, b1 = 0.f;
        #pragma unroll
        for (int j = 0; j < VPT; j += 2) {
            a0 += fminf(wA[j],   eNAa);
            a1 += fminf(wA[j+1], eNAa);
            b0 += fminf(wB[j],   eNAb);
            b1 += fminf(wB[j+1], eNAb);
        }
        float pa = wave_sum(a0 + a1);
        float pb = wave_sum(b0 + b1);
        if (lane == 0) { red[1+t][0][wid] = pa; red[1+t][1][wid] = pb; }
        __syncthreads();
        const float sA_ = red[1+t][0][0] + red[1+t][0][1] + red[1+t][0][2] + red[1+t][0][3];
        const float sB_ = red[1+t][1][0] + red[1+t][1][1] + red[1+t][1][2] + red[1+t][1][3];
        eNAa = (sA_ + 1e-20f) * rkA;
        eNAb = (sB_ + 1e-20f) * rkB;
    }

    // gamma = exp2(min(w - NA, 0)) = min(e, eNA) / eNA. Masked: e=0 -> 0.
    const float ra = 1.0f / eNAa;
    const float rb = 1.0f / eNAb;
    float4* __restrict__ oA = (float4*)(out + (size_t)row0 * SEQ);
    float4* __restrict__ oB = (float4*)(out + (size_t)(row0 + 1) * SEQ);
    #pragma unroll
    for (int j = 0; j < F4PT; ++j) {
        float4 g;
        g.x = fminf(wA[4*j+0], eNAa) * ra;
        g.y = fminf(wA[4*j+1], eNAa) * ra;
        g.z = fminf(wA[4*j+2], eNAa) * ra;
        g.w = fminf(wA[4*j+3], eNAa) * ra;
        oA[j * NTHREADS + tid] = g;
        float4 h;
        h.x = fminf(wB[4*j+0], eNAb) * rb;
        h.y = fminf(wB[4*j+1], eNAb) * rb;
        h.z = fminf(wB[4*j+2], eNAb) * rb;
        h.w = fminf(wB[4*j+3], eNAb) * rb;
        oB[j * NTHREADS + tid] = h;
    }
}

extern "C" void kernel_launch(void* const* d_in, const int* in_sizes, int n_in,
                              void* d_out, int out_size, void* d_ws, size_t ws_size,
                              hipStream_t stream) {
    const float* score = (const float*)d_in[0];
    const int*   mask  = (const int*)d_in[1];
    float*       out   = (float*)d_out;
    const int rows = in_sizes[0] / SEQ;          // 4096
    normalizer_kernel<<<rows / RPB, NTHREADS, 0, stream>>>(score, mask, out);
}